// Round 9
// baseline (132.868 us; speedup 1.0000x reference)
//
#include <hip/hip_runtime.h>
#include <hip/hip_bf16.h>

// BlurredNoise via MFMA implicit GEMM, round 17 = R16 + {step-balance,
// nt-stores, T14 stage-split, A-dist-3}.
// R16 post-mortem: rolled loops fixed I-fetch (81->53us) but (1) k-split was
// step-imbalanced (104 vs 216 steps; occupancy 17% vs 25% = wave0 idle at the
// barrier, tail runs 1 wave/SIMD), (2) FETCH 7.8MB >> inputs: the 39MB output
// write stream floods the 4MB/XCD L2 and evicts the shared swz B-image ->
// B-refills re-miss to HBM. (3) per-window vmcnt(0) stall on x-loads.
// Fixes: W2 re-cut to UB=12 and split 5/1 (wave0 116 steps/312 ts, wave1 204
// steps/216 ts); output via __builtin_nontemporal_store (write-once, never
// read -> keep L2 for swz/x); stage split into load-at-iter-top +
// convert/write-after-step-2U/3 (latency hidden under MFMA steps); A-ring
// prefetch distance 3 (4 slots). All register indices compile-time (rule 20).
// out[bc][F][t] = scale[F] * sum_j x[bc][t+j] * k[F][j]

#define KS      5000
#define IN_SEQ  9095
#define T_OUT   4096
#define NBC     16
#define NF      128
#define SWZSTEP 352               // B rows per tile (s>=313 all-zero via clamp)
#define CSTRIDE 1040              // bytes; /4 = 260 == 4 mod 32 -> uniform banks
#define XBUF    (8*CSTRIDE)       // 8320 B: 8 shifted copies, one window buffer
#define FRONT   128               // xpad front zero pad (floats)
#define XPS     9312              // padded x row stride (floats)
#define SWZ_BYTES (4*SWZSTEP*1024)    // 1,441,792

typedef __attribute__((ext_vector_type(8)))  short v8s;
typedef __attribute__((ext_vector_type(4)))  float v4f;
typedef __attribute__((ext_vector_type(16))) float v16f;

__device__ __forceinline__ unsigned short f2b(float v) {
  union { __hip_bfloat16 h; unsigned short u; } cv;
  cv.h = __float2bfloat16(v);   // RNE
  return cv.u;
}

// ---- fused pre-kernel: (a) filters -> 32x32x16 B-frags; (b) padded x copy ----
__global__ void build_pre(const float* __restrict__ filt,
                          const float* __restrict__ noise,
                          unsigned short* __restrict__ swz,
                          float* __restrict__ xpad) {
  const int b = blockIdx.x;
  if (b < 352) {                       // swz job: 4 tiles x 352 rows, 64 lanes/frag
    const int i = b * 256 + threadIdx.x;
    if (i >= 4 * SWZSTEP * 64) return;
    const int lane = i & 63;
    const int frag = i >> 6;
    const int ft = frag / SWZSTEP;
    const int s  = frag - ft * SWZSTEP;
    const int col = lane & 31;          // filter within tile
    const int hi  = lane >> 5;          // k-group (8 taps)
    const int jg0 = KS - 16 * (s + 1) + 8 * hi;
    const float* row = filt + (size_t)(ft * 32 + col) * KS;
    unsigned short o[8];
    #pragma unroll
    for (int j = 0; j < 8; ++j) {
      int jg = jg0 + j;
      int jc = jg < 0 ? 0 : jg;          // clamp ADDRESS, select VALUE
      float v = (jg >= 0 && jg < KS) ? row[jc] : 0.0f;
      o[j] = f2b(v);
    }
    *(uint4*)(swz + (((size_t)(ft * SWZSTEP + s)) << 9) + (lane << 3)) = *(uint4*)o;
  } else {                             // xpad job: 16 x XPS, zeros outside data
    const int i = (b - 352) * 256 + threadIdx.x;
    if (i >= NBC * XPS) return;
    const int r = i / XPS;
    const int pcol = i - r * XPS;
    const int lg = pcol - FRONT;
    xpad[i] = (lg >= 0 && lg < IN_SEQ) ? noise[r * IN_SEQ + lg] : 0.0f;
  }
}

// ---- one rolled region of the k-loop ----
// W: live 32-F tiles (tiles 4-W..3); UB: steps/window (UB%4==0, UB%D==0);
// D: B-prefetch depth; sb0/iters RUNTIME. Per iter: x-loads for window g+1
// issued at top (T14), converted+written after step SW=2UB/3; UB steps of
// {A ring prefetch dist 3 (2 m-streams), 2W MFMA, W B-refill}. All register
// indices compile-time.
template<int W, int UB, int D>
__device__ __forceinline__ void run_roll(
    const char* __restrict__ swzg, const float* __restrict__ xn,
    char* xw, int xrd_off, int t0, int lane, int sb0, int iters,
    v16f (&acc)[2][4])
{
  constexpr int SW = (2 * UB) / 3;     // stage-write step (< UB-3)
  v8s breg[D][W];
  v8s areg[4][2];                      // [ring slot][m-stream]
  float4 xr[4];                        // in-flight x window (T14 split)

  const char* sp[W];
  #pragma unroll
  for (int w = 0; w < W; ++w)
    sp[w] = swzg + (((size_t)((4 - W + w) * SWZSTEP + sb0)) << 10) + 16 * lane;

  auto stage_load = [&](int sb) {      // issue 4 global loads for window at sb
    const int wb = t0 + KS - 16 * (sb + UB);
    #pragma unroll
    for (int ii = 0; ii < 4; ++ii)
      xr[ii] = *(const float4*)(xn + (wb + 8 * lane + 4 * ii));
  };
  auto stage_write = [&](char* buf) {  // convert + 8 shifted bf16 LDS copies
    const float* f = (const float*)xr;
    unsigned u8v[8];
    #pragma unroll
    for (int j = 0; j < 8; ++j)
      u8v[j] = (unsigned)f2b(f[2 * j]) | ((unsigned)f2b(f[2 * j + 1]) << 16);
    auto AL = [](unsigned hi, unsigned lo) { return (lo >> 16) | (hi << 16); };
    char* bufl = buf + 16 * lane;
    #pragma unroll
    for (int c = 0; c < 8; ++c) {
      const int h = c >> 1;
      uint4 wv;
      if ((c & 1) == 0)
        wv = (uint4){u8v[h], u8v[h + 1], u8v[h + 2], u8v[h + 3]};
      else
        wv = (uint4){AL(u8v[h + 1], u8v[h]),     AL(u8v[h + 2], u8v[h + 1]),
                     AL(u8v[h + 3], u8v[h + 2]), AL(u8v[h + 4], u8v[h + 3])};
      *(uint4*)(bufl + c * CSTRIDE) = wv;
    }
  };

  // prologue: window 0 -> buf0; B depth D; A ring slots 0..2 (steps 0..2)
  stage_load(sb0);
  stage_write(xw);
  #pragma unroll
  for (int d = 0; d < D; ++d)
    #pragma unroll
    for (int w = 0; w < W; ++w)
      breg[d][w] = *(const v8s*)(sp[w] + (d << 10));
  {
    const char* xrd0 = xw + xrd_off;
    #pragma unroll
    for (int j = 0; j < 3; ++j)
      #pragma unroll
      for (int m = 0; m < 2; ++m)
        areg[j][m] = *(const v8s*)(xrd0 + 64 * m + 32 * (UB - 1 - j));
  }

  #pragma unroll 1
  for (int g = 0; g < iters; ++g) {
    char* bufn = xw + (((g + 1) & 1) ? XBUF : 0);     // next window buffer
    const char* xrd  = xw + ((g & 1) ? XBUF : 0) + xrd_off;
    const char* xrdn = bufn + xrd_off;
    const int sbn = sb0 + UB * ((g + 1 < iters) ? g + 1 : g);  // clamp restage
    stage_load(sbn);                   // issue early; consumed at ii==SW
    #pragma unroll
    for (int ii = 0; ii < UB; ++ii) {
      // A prefetch for step ii+3 (crosses into next window at ii>=UB-3)
      {
        const char* pn = (ii + 3 < UB) ? xrd : xrdn;
        const int off = (ii + 3 < UB) ? 32 * (UB - 4 - ii) : 32 * (2 * UB - 4 - ii);
        #pragma unroll
        for (int m = 0; m < 2; ++m)
          areg[(ii + 3) & 3][m] = *(const v8s*)(pn + 64 * m + off);
      }
      // MFMA: one A fragment per m-stream x W live B tiles (B shared)
      #pragma unroll
      for (int w = 0; w < W; ++w)
        #pragma unroll
        for (int m = 0; m < 2; ++m)
          acc[m][4 - W + w] = __builtin_amdgcn_mfma_f32_32x32x16_bf16(
              areg[ii & 3][m], breg[ii % D][w], acc[m][4 - W + w], 0, 0, 0);
      // T14 write-late: x latency hidden under SW steps of MFMA; LDS FIFO
      // order guarantees these writes complete before the ii>=UB-3 reads.
      if (ii == SW) stage_write(bufn);
      // B refill: slot ii%D <- step ii+D (tail over-reads: rows < SWZSTEP, dead)
      #pragma unroll
      for (int w = 0; w < W; ++w)
        breg[ii % D][w] = *(const v8s*)(sp[w] + ((ii + D) << 10));
    }
    #pragma unroll
    for (int w = 0; w < W; ++w) sp[w] += (UB << 10);
  }
}

// ---- main kernel: 1024 blocks x 128 threads (2 waves k-split one 64t tile) ----
__global__ __launch_bounds__(128, 2) void blur_mfma(
    const float* __restrict__ xpad,
    const unsigned short* __restrict__ swz,
    const float* __restrict__ scale,
    float* __restrict__ out)
{
  __shared__ __align__(16) char xb[2 * 2 * XBUF];   // 33,280 B (2 waves x dbuf)
  const int tid  = threadIdx.x;
  const int lane = tid & 63;
  const int wid  = tid >> 6;
  const int b  = blockIdx.x;
  const int bc = b >> 6;                 // 16 bc x 64 t-chunks
  const int t0 = (b & 63) << 6;          // 64 output t per block (2 m-tiles)
  const int row = lane & 31, hi = lane >> 5;
  const float* __restrict__ xn = xpad + (size_t)bc * XPS + FRONT;
  const char* swzg = (const char*)swz;
  char* xw = xb + wid * (2 * XBUF);      // this wave's double-buffered region
  // A-read: copy c=row&7, byte 16*(row>>3) + 16*hi (+32/step, +64/m-stream)
  const int xrd_off = (row & 7) * CSTRIDE + 16 * (row >> 3) + 16 * hi;

  v16f acc[2][4];
  #pragma unroll
  for (int m = 0; m < 2; ++m)
    #pragma unroll
    for (int n = 0; n < 4; ++n)
      #pragma unroll
      for (int j = 0; j < 16; ++j) acc[m][n][j] = 0.0f;

  // regions (live: W4 s<20, W3 <49, W2 <124, W1 <313; extras hit zero B rows)
  // wave0: W4 0..23 + W3 24..55 + W2 56..115   (116 steps, 312 tile-steps)
  // wave1: W2 116..127 + W1 128..319           (204 steps, 216 tile-steps)
  if (wid == 0) {
    run_roll<4, 24,  3>(swzg, xn, xw, xrd_off, t0, lane,   0, 1, acc);
    run_roll<3, 16,  4>(swzg, xn, xw, xrd_off, t0, lane,  24, 2, acc);
    run_roll<2, 12,  6>(swzg, xn, xw, xrd_off, t0, lane,  56, 5, acc);
  } else {
    run_roll<2, 12,  6>(swzg, xn, xw, xrd_off, t0, lane, 116, 1, acc);
    run_roll<1, 24, 12>(swzg, xn, xw, xrd_off, t0, lane, 128, 8, acc);
  }

  // cross-wave reduction: 2 rounds of 16KB through the (dead) x region.
  __syncthreads();
  #pragma unroll
  for (int mm = 0; mm < 2; ++mm) {
    if (wid == 1) {
      #pragma unroll
      for (int n = 0; n < 4; ++n)
        #pragma unroll
        for (int r2 = 0; r2 < 4; ++r2) {
          v4f v = {acc[mm][n][4 * r2],     acc[mm][n][4 * r2 + 1],
                   acc[mm][n][4 * r2 + 2], acc[mm][n][4 * r2 + 3]};
          *(v4f*)(xb + ((n * 4 + r2) << 10) + 16 * lane) = v;
        }
    }
    __syncthreads();
    if (wid == 0) {
      #pragma unroll
      for (int n = 0; n < 4; ++n)
        #pragma unroll
        for (int r2 = 0; r2 < 4; ++r2) {
          v4f v = *(const v4f*)(xb + ((n * 4 + r2) << 10) + 16 * lane);
          acc[mm][n][4 * r2]     += v[0];
          acc[mm][n][4 * r2 + 1] += v[1];
          acc[mm][n][4 * r2 + 2] += v[2];
          acc[mm][n][4 * r2 + 3] += v[3];
        }
    }
    __syncthreads();                   // WAR guard before next round's writes
  }

  // epilogue (wave0): nt stores (write-once stream; keep L2 for swz/x).
  // D col=lane&31 -> F, row=(reg&3)+8*(reg>>2)+4*hi -> t
  if (wid == 0) {
    #pragma unroll
    for (int m = 0; m < 2; ++m)
      #pragma unroll
      for (int n = 0; n < 4; ++n) {
        const int F = 32 * n + row;
        const float sc = scale[F];
        float* op = out + (size_t)(bc * NF + F) * T_OUT + t0 + 32 * m + 4 * hi;
        #pragma unroll
        for (int r2 = 0; r2 < 4; ++r2) {
          v4f o = {acc[m][n][4 * r2] * sc, acc[m][n][4 * r2 + 1] * sc,
                   acc[m][n][4 * r2 + 2] * sc, acc[m][n][4 * r2 + 3] * sc};
          __builtin_nontemporal_store(o, (v4f*)(op + 8 * r2));
        }
      }
  }
}

extern "C" void kernel_launch(void* const* d_in, const int* in_sizes, int n_in,
                              void* d_out, int out_size, void* d_ws, size_t ws_size,
                              hipStream_t stream) {
  const float* noise = (const float*)d_in[0];   // (2, 8, 9095) fp32
  const float* filt  = (const float*)d_in[1];   // (128, 5000) fp32
  const float* scale = (const float*)d_in[2];   // (1, 128, 1) fp32
  float* out = (float*)d_out;                   // (2, 1024, 4096) fp32

  unsigned short* swz = (unsigned short*)d_ws;              // 1.44 MB
  float* xpad = (float*)((char*)d_ws + SWZ_BYTES);          // 16 x 9312 fp32

  const int pad_blocks = (NBC * XPS + 255) / 256;           // 582
  build_pre<<<352 + pad_blocks, 256, 0, stream>>>(filt, noise, swz, xpad);
  blur_mfma<<<1024, 128, 0, stream>>>(xpad, swz, scale, out);
}

// Round 10
// 117.613 us; speedup vs baseline: 1.1297x; 1.1297x over previous
//
#include <hip/hip_runtime.h>
#include <hip/hip_bf16.h>

// BlurredNoise via MFMA implicit GEMM, round 18 = R17 minus nt-stores.
// R17 post-mortem: __builtin_nontemporal_store on 16B-scattered epilogue
// stores defeated L2 write-merging -> partial-sector RMW at HBM: WRITE_SIZE
// 39->78MB, FETCH 7.8->10.7MB, +41MB/pass at 1.28TB/s = the whole +17us
// regression (kernel became HBM-write-bound, MfmaUtil 26->18.5). Fix: plain
// cached stores (L2 merges the 8 instrs covering each row's 128B). KEEP
// R17's other three changes to measure them cleanly vs R16's 53.4us:
// step-balanced k-split (wave0 116 steps/312ts, wave1 204/216), T14
// stage-split (x loads at iter top, convert+LDS-write at step 2UB/3),
// A-ring prefetch distance 3. All register indices compile-time (rule 20).
// out[bc][F][t] = scale[F] * sum_j x[bc][t+j] * k[F][j]

#define KS      5000
#define IN_SEQ  9095
#define T_OUT   4096
#define NBC     16
#define NF      128
#define SWZSTEP 352               // B rows per tile (s>=313 all-zero via clamp)
#define CSTRIDE 1040              // bytes; /4 = 260 == 4 mod 32 -> uniform banks
#define XBUF    (8*CSTRIDE)       // 8320 B: 8 shifted copies, one window buffer
#define FRONT   128               // xpad front zero pad (floats)
#define XPS     9312              // padded x row stride (floats)
#define SWZ_BYTES (4*SWZSTEP*1024)    // 1,441,792

typedef __attribute__((ext_vector_type(8)))  short v8s;
typedef __attribute__((ext_vector_type(4)))  float v4f;
typedef __attribute__((ext_vector_type(16))) float v16f;

__device__ __forceinline__ unsigned short f2b(float v) {
  union { __hip_bfloat16 h; unsigned short u; } cv;
  cv.h = __float2bfloat16(v);   // RNE
  return cv.u;
}

// ---- fused pre-kernel: (a) filters -> 32x32x16 B-frags; (b) padded x copy ----
__global__ void build_pre(const float* __restrict__ filt,
                          const float* __restrict__ noise,
                          unsigned short* __restrict__ swz,
                          float* __restrict__ xpad) {
  const int b = blockIdx.x;
  if (b < 352) {                       // swz job: 4 tiles x 352 rows, 64 lanes/frag
    const int i = b * 256 + threadIdx.x;
    if (i >= 4 * SWZSTEP * 64) return;
    const int lane = i & 63;
    const int frag = i >> 6;
    const int ft = frag / SWZSTEP;
    const int s  = frag - ft * SWZSTEP;
    const int col = lane & 31;          // filter within tile
    const int hi  = lane >> 5;          // k-group (8 taps)
    const int jg0 = KS - 16 * (s + 1) + 8 * hi;
    const float* row = filt + (size_t)(ft * 32 + col) * KS;
    unsigned short o[8];
    #pragma unroll
    for (int j = 0; j < 8; ++j) {
      int jg = jg0 + j;
      int jc = jg < 0 ? 0 : jg;          // clamp ADDRESS, select VALUE
      float v = (jg >= 0 && jg < KS) ? row[jc] : 0.0f;
      o[j] = f2b(v);
    }
    *(uint4*)(swz + (((size_t)(ft * SWZSTEP + s)) << 9) + (lane << 3)) = *(uint4*)o;
  } else {                             // xpad job: 16 x XPS, zeros outside data
    const int i = (b - 352) * 256 + threadIdx.x;
    if (i >= NBC * XPS) return;
    const int r = i / XPS;
    const int pcol = i - r * XPS;
    const int lg = pcol - FRONT;
    xpad[i] = (lg >= 0 && lg < IN_SEQ) ? noise[r * IN_SEQ + lg] : 0.0f;
  }
}

// ---- one rolled region of the k-loop ----
// W: live 32-F tiles (tiles 4-W..3); UB: steps/window (UB%4==0, UB%D==0);
// D: B-prefetch depth; sb0/iters RUNTIME. Per iter: x-loads for window g+1
// issued at top (T14), converted+written after step SW=2UB/3; UB steps of
// {A ring prefetch dist 3 (2 m-streams), 2W MFMA, W B-refill}. All register
// indices compile-time.
template<int W, int UB, int D>
__device__ __forceinline__ void run_roll(
    const char* __restrict__ swzg, const float* __restrict__ xn,
    char* xw, int xrd_off, int t0, int lane, int sb0, int iters,
    v16f (&acc)[2][4])
{
  constexpr int SW = (2 * UB) / 3;     // stage-write step (< UB-3)
  v8s breg[D][W];
  v8s areg[4][2];                      // [ring slot][m-stream]
  float4 xr[4];                        // in-flight x window (T14 split)

  const char* sp[W];
  #pragma unroll
  for (int w = 0; w < W; ++w)
    sp[w] = swzg + (((size_t)((4 - W + w) * SWZSTEP + sb0)) << 10) + 16 * lane;

  auto stage_load = [&](int sb) {      // issue 4 global loads for window at sb
    const int wb = t0 + KS - 16 * (sb + UB);
    #pragma unroll
    for (int ii = 0; ii < 4; ++ii)
      xr[ii] = *(const float4*)(xn + (wb + 8 * lane + 4 * ii));
  };
  auto stage_write = [&](char* buf) {  // convert + 8 shifted bf16 LDS copies
    const float* f = (const float*)xr;
    unsigned u8v[8];
    #pragma unroll
    for (int j = 0; j < 8; ++j)
      u8v[j] = (unsigned)f2b(f[2 * j]) | ((unsigned)f2b(f[2 * j + 1]) << 16);
    auto AL = [](unsigned hi, unsigned lo) { return (lo >> 16) | (hi << 16); };
    char* bufl = buf + 16 * lane;
    #pragma unroll
    for (int c = 0; c < 8; ++c) {
      const int h = c >> 1;
      uint4 wv;
      if ((c & 1) == 0)
        wv = (uint4){u8v[h], u8v[h + 1], u8v[h + 2], u8v[h + 3]};
      else
        wv = (uint4){AL(u8v[h + 1], u8v[h]),     AL(u8v[h + 2], u8v[h + 1]),
                     AL(u8v[h + 3], u8v[h + 2]), AL(u8v[h + 4], u8v[h + 3])};
      *(uint4*)(bufl + c * CSTRIDE) = wv;
    }
  };

  // prologue: window 0 -> buf0; B depth D; A ring slots 0..2 (steps 0..2)
  stage_load(sb0);
  stage_write(xw);
  #pragma unroll
  for (int d = 0; d < D; ++d)
    #pragma unroll
    for (int w = 0; w < W; ++w)
      breg[d][w] = *(const v8s*)(sp[w] + (d << 10));
  {
    const char* xrd0 = xw + xrd_off;
    #pragma unroll
    for (int j = 0; j < 3; ++j)
      #pragma unroll
      for (int m = 0; m < 2; ++m)
        areg[j][m] = *(const v8s*)(xrd0 + 64 * m + 32 * (UB - 1 - j));
  }

  #pragma unroll 1
  for (int g = 0; g < iters; ++g) {
    char* bufn = xw + (((g + 1) & 1) ? XBUF : 0);     // next window buffer
    const char* xrd  = xw + ((g & 1) ? XBUF : 0) + xrd_off;
    const char* xrdn = bufn + xrd_off;
    const int sbn = sb0 + UB * ((g + 1 < iters) ? g + 1 : g);  // clamp restage
    stage_load(sbn);                   // issue early; consumed at ii==SW
    #pragma unroll
    for (int ii = 0; ii < UB; ++ii) {
      // A prefetch for step ii+3 (crosses into next window at ii>=UB-3)
      {
        const char* pn = (ii + 3 < UB) ? xrd : xrdn;
        const int off = (ii + 3 < UB) ? 32 * (UB - 4 - ii) : 32 * (2 * UB - 4 - ii);
        #pragma unroll
        for (int m = 0; m < 2; ++m)
          areg[(ii + 3) & 3][m] = *(const v8s*)(pn + 64 * m + off);
      }
      // MFMA: one A fragment per m-stream x W live B tiles (B shared)
      #pragma unroll
      for (int w = 0; w < W; ++w)
        #pragma unroll
        for (int m = 0; m < 2; ++m)
          acc[m][4 - W + w] = __builtin_amdgcn_mfma_f32_32x32x16_bf16(
              areg[ii & 3][m], breg[ii % D][w], acc[m][4 - W + w], 0, 0, 0);
      // T14 write-late: x latency hidden under SW steps of MFMA; LDS FIFO
      // order guarantees these writes complete before the ii>=UB-3 reads.
      if (ii == SW) stage_write(bufn);
      // B refill: slot ii%D <- step ii+D (tail over-reads: rows < SWZSTEP, dead)
      #pragma unroll
      for (int w = 0; w < W; ++w)
        breg[ii % D][w] = *(const v8s*)(sp[w] + ((ii + D) << 10));
    }
    #pragma unroll
    for (int w = 0; w < W; ++w) sp[w] += (UB << 10);
  }
}

// ---- main kernel: 1024 blocks x 128 threads (2 waves k-split one 64t tile) ----
__global__ __launch_bounds__(128, 2) void blur_mfma(
    const float* __restrict__ xpad,
    const unsigned short* __restrict__ swz,
    const float* __restrict__ scale,
    float* __restrict__ out)
{
  __shared__ __align__(16) char xb[2 * 2 * XBUF];   // 33,280 B (2 waves x dbuf)
  const int tid  = threadIdx.x;
  const int lane = tid & 63;
  const int wid  = tid >> 6;
  const int b  = blockIdx.x;
  const int bc = b >> 6;                 // 16 bc x 64 t-chunks
  const int t0 = (b & 63) << 6;          // 64 output t per block (2 m-tiles)
  const int row = lane & 31, hi = lane >> 5;
  const float* __restrict__ xn = xpad + (size_t)bc * XPS + FRONT;
  const char* swzg = (const char*)swz;
  char* xw = xb + wid * (2 * XBUF);      // this wave's double-buffered region
  // A-read: copy c=row&7, byte 16*(row>>3) + 16*hi (+32/step, +64/m-stream)
  const int xrd_off = (row & 7) * CSTRIDE + 16 * (row >> 3) + 16 * hi;

  v16f acc[2][4];
  #pragma unroll
  for (int m = 0; m < 2; ++m)
    #pragma unroll
    for (int n = 0; n < 4; ++n)
      #pragma unroll
      for (int j = 0; j < 16; ++j) acc[m][n][j] = 0.0f;

  // regions (live: W4 s<20, W3 <49, W2 <124, W1 <313; extras hit zero B rows)
  // wave0: W4 0..23 + W3 24..55 + W2 56..115   (116 steps, 312 tile-steps)
  // wave1: W2 116..127 + W1 128..319           (204 steps, 216 tile-steps)
  if (wid == 0) {
    run_roll<4, 24,  3>(swzg, xn, xw, xrd_off, t0, lane,   0, 1, acc);
    run_roll<3, 16,  4>(swzg, xn, xw, xrd_off, t0, lane,  24, 2, acc);
    run_roll<2, 12,  6>(swzg, xn, xw, xrd_off, t0, lane,  56, 5, acc);
  } else {
    run_roll<2, 12,  6>(swzg, xn, xw, xrd_off, t0, lane, 116, 1, acc);
    run_roll<1, 24, 12>(swzg, xn, xw, xrd_off, t0, lane, 128, 8, acc);
  }

  // cross-wave reduction: 2 rounds of 16KB through the (dead) x region.
  __syncthreads();
  #pragma unroll
  for (int mm = 0; mm < 2; ++mm) {
    if (wid == 1) {
      #pragma unroll
      for (int n = 0; n < 4; ++n)
        #pragma unroll
        for (int r2 = 0; r2 < 4; ++r2) {
          v4f v = {acc[mm][n][4 * r2],     acc[mm][n][4 * r2 + 1],
                   acc[mm][n][4 * r2 + 2], acc[mm][n][4 * r2 + 3]};
          *(v4f*)(xb + ((n * 4 + r2) << 10) + 16 * lane) = v;
        }
    }
    __syncthreads();
    if (wid == 0) {
      #pragma unroll
      for (int n = 0; n < 4; ++n)
        #pragma unroll
        for (int r2 = 0; r2 < 4; ++r2) {
          v4f v = *(const v4f*)(xb + ((n * 4 + r2) << 10) + 16 * lane);
          acc[mm][n][4 * r2]     += v[0];
          acc[mm][n][4 * r2 + 1] += v[1];
          acc[mm][n][4 * r2 + 2] += v[2];
          acc[mm][n][4 * r2 + 3] += v[3];
        }
    }
    __syncthreads();                   // WAR guard before next round's writes
  }

  // epilogue (wave0): plain cached stores (L2 merges the 8 instrs covering
  // each row's 128B -> full-line writebacks; nt-stores caused RMW, R17).
  // D col=lane&31 -> F, row=(reg&3)+8*(reg>>2)+4*hi -> t
  if (wid == 0) {
    #pragma unroll
    for (int m = 0; m < 2; ++m)
      #pragma unroll
      for (int n = 0; n < 4; ++n) {
        const int F = 32 * n + row;
        const float sc = scale[F];
        float* op = out + (size_t)(bc * NF + F) * T_OUT + t0 + 32 * m + 4 * hi;
        #pragma unroll
        for (int r2 = 0; r2 < 4; ++r2) {
          v4f o = {acc[m][n][4 * r2] * sc, acc[m][n][4 * r2 + 1] * sc,
                   acc[m][n][4 * r2 + 2] * sc, acc[m][n][4 * r2 + 3] * sc};
          *(v4f*)(op + 8 * r2) = o;
        }
      }
  }
}

extern "C" void kernel_launch(void* const* d_in, const int* in_sizes, int n_in,
                              void* d_out, int out_size, void* d_ws, size_t ws_size,
                              hipStream_t stream) {
  const float* noise = (const float*)d_in[0];   // (2, 8, 9095) fp32
  const float* filt  = (const float*)d_in[1];   // (128, 5000) fp32
  const float* scale = (const float*)d_in[2];   // (1, 128, 1) fp32
  float* out = (float*)d_out;                   // (2, 1024, 4096) fp32

  unsigned short* swz = (unsigned short*)d_ws;              // 1.44 MB
  float* xpad = (float*)((char*)d_ws + SWZ_BYTES);          // 16 x 9312 fp32

  const int pad_blocks = (NBC * XPS + 255) / 256;           // 582
  build_pre<<<352 + pad_blocks, 256, 0, stream>>>(filt, noise, swz, xpad);
  blur_mfma<<<1024, 128, 0, stream>>>(xpad, swz, scale, out);
}